// Round 8
// baseline (930.808 us; speedup 1.0000x reference)
//
#include <hip/hip_runtime.h>

#define D_INF 64
#define DEF 16   // edge feature dim
#define HF 16    // hidden dim

// ---------------- CSR build ----------------

__global__ __launch_bounds__(256) void k_hist(const int* __restrict__ dst, int E, int* __restrict__ deg) {
    int i = blockIdx.x * blockDim.x + threadIdx.x;
    if (i < E) atomicAdd(&deg[dst[i]], 1);
}

#define SCAN_B 256
__global__ __launch_bounds__(SCAN_B) void k_scan_partial(const int* __restrict__ deg, int N, int* __restrict__ partial) {
    __shared__ int s[SCAN_B];
    int i = blockIdx.x * SCAN_B + threadIdx.x;
    s[threadIdx.x] = (i < N) ? deg[i] : 0;
    __syncthreads();
    for (int off = SCAN_B / 2; off > 0; off >>= 1) {
        if (threadIdx.x < off) s[threadIdx.x] += s[threadIdx.x + off];
        __syncthreads();
    }
    if (threadIdx.x == 0) partial[blockIdx.x] = s[0];
}

__global__ __launch_bounds__(1024) void k_scan_top(int* __restrict__ partial, int P) {
    __shared__ int s[1024];
    int t = threadIdx.x;
    int orig = (t < P) ? partial[t] : 0;
    s[t] = orig;
    __syncthreads();
    for (int o = 1; o < 1024; o <<= 1) {
        int v = (t >= o) ? s[t - o] : 0;
        __syncthreads();
        s[t] += v;
        __syncthreads();
    }
    if (t < P) partial[t] = s[t] - orig;   // exclusive prefix of chunk sums
}

__global__ __launch_bounds__(SCAN_B) void k_scan_final(const int* __restrict__ deg, const int* __restrict__ partial,
                                                       int N, int* __restrict__ row_ptr, int* __restrict__ cursor) {
    __shared__ int s[SCAN_B];
    int t = threadIdx.x;
    int i = blockIdx.x * SCAN_B + t;
    int d = (i < N) ? deg[i] : 0;
    s[t] = d;
    __syncthreads();
    for (int o = 1; o < SCAN_B; o <<= 1) {
        int v = (t >= o) ? s[t - o] : 0;
        __syncthreads();
        s[t] += v;
        __syncthreads();
    }
    int excl = s[t] - d + partial[blockIdx.x];
    if (i < N) {
        row_ptr[i] = excl;
        cursor[i] = excl;
        if (i == N - 1) row_ptr[N] = excl + d;
    }
}

__global__ __launch_bounds__(256) void k_scatter(const int* __restrict__ src, const int* __restrict__ dst, int E,
                                                 int* __restrict__ cursor, int2* __restrict__ csr_se) {
    int e = blockIdx.x * blockDim.x + threadIdx.x;
    if (e < E) {
        int d = dst[e];
        int pos = atomicAdd(&cursor[d], 1);
        csr_se[pos] = make_int2(src[e], e);   // one 8B write instead of 2x4B to two arrays
    }
}

// ---------------- prep: xt1 = x @ Wm1[0:64,:], s1 = x @ Ws1 + bs1 ----------------
__global__ __launch_bounds__(256) void k_prep(const float* __restrict__ x,
                                              const float* __restrict__ Wm1,
                                              const float* __restrict__ Ws1,
                                              const float* __restrict__ bs1,
                                              int N, float* __restrict__ xt1, float* __restrict__ s1) {
    int t = blockIdx.x * blockDim.x + threadIdx.x;
    int n = t >> 4, f = t & 15;
    if (n >= N) return;
    const float4* xr4 = (const float4*)(x + (size_t)n * D_INF);
    float am = 0.f, as = bs1[f];
#pragma unroll
    for (int k4 = 0; k4 < 16; k4++) {
        float4 v = xr4[k4];
        int k = 4 * k4;
        am += v.x * Wm1[(k + 0) * HF + f]; as += v.x * Ws1[(k + 0) * HF + f];
        am += v.y * Wm1[(k + 1) * HF + f]; as += v.y * Ws1[(k + 1) * HF + f];
        am += v.z * Wm1[(k + 2) * HF + f]; as += v.z * Ws1[(k + 2) * HF + f];
        am += v.w * Wm1[(k + 3) * HF + f]; as += v.w * Ws1[(k + 3) * HF + f];
    }
    size_t idx = (size_t)n * HF + f;
    xt1[idx] = am;
    s1[idx]  = as;
}

// ---------------- conv1 fused: gather + node MLP -> xt2, h2base ----------------
// wave per node: 4 edge-slots x 16 features; no LDS, no atomics.
// Gather loop unrolled x4: 4 independent int2 index loads then 8 gathers per thread
// -> 16 gather lines in flight per wave (latency hedge).
// After the two xor-reduces ALL 64 lanes hold the full sums for feature f=lane&15,
// so the 16-wide node MLP runs in-wave (4 redundant copies, free) -- no aggm/agge round trip.
// h1 = relu(aggm + deg*b1 + agge@Wm1[64:80] + s1);  xt2 = h1@Wm2[0:16];
// h2base = h1@Ws2 + bs2 + agge@Wm2[16:32]
__global__ __launch_bounds__(256) void k_conv1f(const float* __restrict__ xt1, const float* __restrict__ eattr,
                                                const int2* __restrict__ csr_se, const int* __restrict__ row_ptr,
                                                const float* __restrict__ s1,
                                                const float* __restrict__ Wm1, const float* __restrict__ b1,
                                                const float* __restrict__ Wm2,
                                                const float* __restrict__ Ws2, const float* __restrict__ bs2,
                                                int N, float* __restrict__ xt2, float* __restrict__ h2base) {
    int lane = threadIdx.x & 63;
    int node = (int)((blockIdx.x * blockDim.x + threadIdx.x) >> 6);
    if (node >= N) return;
    int sub = lane >> 4, f = lane & 15;
    int r0 = row_ptr[node], r1 = row_ptr[node + 1];
    float degf = (float)(r1 - r0);
    float am = 0.f, ae = 0.f;
    int j = r0 + sub;
    for (; j + 12 < r1; j += 16) {         // unroll x4: indices j, j+4, j+8, j+12
        int2 se0 = csr_se[j];
        int2 se1 = csr_se[j + 4];
        int2 se2 = csr_se[j + 8];
        int2 se3 = csr_se[j + 12];
        float m0 = xt1[(size_t)se0.x * HF + f];
        float m1 = xt1[(size_t)se1.x * HF + f];
        float m2 = xt1[(size_t)se2.x * HF + f];
        float m3 = xt1[(size_t)se3.x * HF + f];
        float e0 = __builtin_nontemporal_load(eattr + (size_t)se0.y * DEF + f);
        float e1 = __builtin_nontemporal_load(eattr + (size_t)se1.y * DEF + f);
        float e2 = __builtin_nontemporal_load(eattr + (size_t)se2.y * DEF + f);
        float e3 = __builtin_nontemporal_load(eattr + (size_t)se3.y * DEF + f);
        am += (m0 + m1) + (m2 + m3);
        ae += (e0 + e1) + (e2 + e3);
    }
    for (; j < r1; j += 4) {               // remainder (0..3 indices for this sub)
        int2 se = csr_se[j];
        am += xt1[(size_t)se.x * HF + f];
        ae += __builtin_nontemporal_load(eattr + (size_t)se.y * DEF + f);
    }
    am += __shfl_xor(am, 16); am += __shfl_xor(am, 32);
    ae += __shfl_xor(ae, 16); ae += __shfl_xor(ae, 32);

    size_t idx = (size_t)node * HF + f;
    float acc = am + degf * b1[f] + s1[idx];
#pragma unroll
    for (int k = 0; k < HF; k++) {
        acc += __shfl(ae, k, 16) * Wm1[(D_INF + k) * HF + f];
    }
    float h1 = fmaxf(acc, 0.f);
    float xv = 0.f, hb = bs2[f];
#pragma unroll
    for (int k = 0; k < HF; k++) {
        float hk = __shfl(h1, k, 16);
        float ak = __shfl(ae, k, 16);
        xv += hk * Wm2[k * HF + f];
        hb += hk * Ws2[k * HF + f];
        hb += ak * Wm2[(HF + k) * HF + f];
    }
    if (lane < 16) {
        xt2[idx]    = xv;
        h2base[idx] = hb;
    }
}

// ---------------- conv2 fused: gather + final projection -> out ----------------
// h2 = sum xt2[src] + deg*b2 + h2base;  out = h2 @ W3 + b3  (width-16 shfl broadcast)
__global__ __launch_bounds__(256) void k_conv2f(const float* __restrict__ xt2,
                                                const int2* __restrict__ csr_se, const int* __restrict__ row_ptr,
                                                const float* __restrict__ h2base, const float* __restrict__ b2,
                                                const float* __restrict__ W3, const float* __restrict__ b3,
                                                int N, float* __restrict__ out) {
    int lane = threadIdx.x & 63;
    int node = (int)((blockIdx.x * blockDim.x + threadIdx.x) >> 6);
    if (node >= N) return;
    int sub = lane >> 4, f = lane & 15;
    int r0 = row_ptr[node], r1 = row_ptr[node + 1];
    float acc = 0.f;
    int j = r0 + sub;
    for (; j + 12 < r1; j += 16) {         // unroll x4
        int s0 = csr_se[j].x;
        int s1i = csr_se[j + 4].x;
        int s2 = csr_se[j + 8].x;
        int s3 = csr_se[j + 12].x;
        acc += xt2[(size_t)s0 * HF + f] + xt2[(size_t)s1i * HF + f];
        acc += xt2[(size_t)s2 * HF + f] + xt2[(size_t)s3 * HF + f];
    }
    for (; j < r1; j += 4) acc += xt2[(size_t)csr_se[j].x * HF + f];
    acc += __shfl_xor(acc, 16);
    acc += __shfl_xor(acc, 32);

    float h2 = acc + (float)(r1 - r0) * b2[f] + h2base[(size_t)node * HF + f];
    float o = b3[lane];
#pragma unroll
    for (int k = 0; k < HF; k++) {
        o += __shfl(h2, k, 16) * W3[k * D_INF + lane];   // segments identical -> width-16 ok
    }
    out[(size_t)node * D_INF + lane] = o;
}

// ---------------- launch ----------------

static inline size_t align256(size_t x) { return (x + 255) & ~(size_t)255; }

extern "C" void kernel_launch(void* const* d_in, const int* in_sizes, int n_in,
                              void* d_out, int out_size, void* d_ws, size_t ws_size,
                              hipStream_t stream) {
    const float* x    = (const float*)d_in[0];
    const int*   ei   = (const int*)d_in[1];
    const float* eatt = (const float*)d_in[2];
    const float* Wm1  = (const float*)d_in[3];
    const float* b1   = (const float*)d_in[4];
    const float* Ws1  = (const float*)d_in[5];
    const float* bs1  = (const float*)d_in[6];
    const float* Wm2  = (const float*)d_in[7];
    const float* b2   = (const float*)d_in[8];
    const float* Ws2  = (const float*)d_in[9];
    const float* bs2  = (const float*)d_in[10];
    const float* W3   = (const float*)d_in[11];
    const float* b3   = (const float*)d_in[12];
    float* out = (float*)d_out;

    int N = in_sizes[0] / D_INF;
    int E = in_sizes[1] / 2;
    const int* src = ei;
    const int* dst = ei + E;

    char* ws = (char*)d_ws;
    size_t off = 0;
    auto alloc = [&](size_t bytes) -> void* { void* p = ws + off; off = align256(off + bytes); return p; };

    int*   deg     = (int*)alloc((size_t)N * 4);
    int*   row_ptr = (int*)alloc((size_t)(N + 1) * 4);
    int*   cursor  = (int*)alloc((size_t)N * 4);
    int*   partial = (int*)alloc(1024 * 4);
    int2*  csr_se  = (int2*)alloc((size_t)E * 8);
    size_t szA = (size_t)N * HF * sizeof(float);
    float* xt1     = (float*)alloc(szA);
    float* s1      = (float*)alloc(szA);
    float* xt2     = (float*)alloc(szA);
    float* h2base  = (float*)alloc(szA);
    (void)ws_size; (void)n_in; (void)out_size;

    int P = (N + SCAN_B - 1) / SCAN_B;   // 391 for N=100k; k_scan_top handles P<=1024

    hipMemsetAsync(deg, 0, (size_t)N * 4, stream);

    dim3 blk(256);
    int gN16 = (N * HF + 255) / 256;

    k_hist        <<<dim3((E + 255) / 256), blk, 0, stream>>>(dst, E, deg);
    k_scan_partial<<<dim3(P), dim3(SCAN_B), 0, stream>>>(deg, N, partial);
    k_scan_top    <<<dim3(1), dim3(1024), 0, stream>>>(partial, P);
    k_scan_final  <<<dim3(P), dim3(SCAN_B), 0, stream>>>(deg, partial, N, row_ptr, cursor);
    k_scatter     <<<dim3((E + 255) / 256), blk, 0, stream>>>(src, dst, E, cursor, csr_se);

    k_prep  <<<dim3(gN16), blk, 0, stream>>>(x, Wm1, Ws1, bs1, N, xt1, s1);
    k_conv1f<<<dim3((N + 3) / 4), blk, 0, stream>>>(xt1, eatt, csr_se, row_ptr, s1,
                                                    Wm1, b1, Wm2, Ws2, bs2, N, xt2, h2base);
    k_conv2f<<<dim3((N + 3) / 4), blk, 0, stream>>>(xt2, csr_se, row_ptr, h2base, b2,
                                                    W3, b3, N, out);
}

// Round 12
// 784.725 us; speedup vs baseline: 1.1862x; 1.1862x over previous
//
#include <hip/hip_runtime.h>

#define D_INF 64
#define DEF 16   // edge feature dim
#define HF 16    // hidden dim

// ---------------- CSR build ----------------

__global__ __launch_bounds__(256) void k_hist(const int* __restrict__ dst, int E, int* __restrict__ deg) {
    int i = blockIdx.x * blockDim.x + threadIdx.x;
    if (i < E) atomicAdd(&deg[dst[i]], 1);
}

#define SCAN_B 256
__global__ __launch_bounds__(SCAN_B) void k_scan_partial(const int* __restrict__ deg, int N, int* __restrict__ partial) {
    __shared__ int s[SCAN_B];
    int i = blockIdx.x * SCAN_B + threadIdx.x;
    s[threadIdx.x] = (i < N) ? deg[i] : 0;
    __syncthreads();
    for (int off = SCAN_B / 2; off > 0; off >>= 1) {
        if (threadIdx.x < off) s[threadIdx.x] += s[threadIdx.x + off];
        __syncthreads();
    }
    if (threadIdx.x == 0) partial[blockIdx.x] = s[0];
}

__global__ __launch_bounds__(1024) void k_scan_top(int* __restrict__ partial, int P) {
    __shared__ int s[1024];
    int t = threadIdx.x;
    int orig = (t < P) ? partial[t] : 0;
    s[t] = orig;
    __syncthreads();
    for (int o = 1; o < 1024; o <<= 1) {
        int v = (t >= o) ? s[t - o] : 0;
        __syncthreads();
        s[t] += v;
        __syncthreads();
    }
    if (t < P) partial[t] = s[t] - orig;   // exclusive prefix of chunk sums
}

__global__ __launch_bounds__(SCAN_B) void k_scan_final(const int* __restrict__ deg, const int* __restrict__ partial,
                                                       int N, int* __restrict__ row_ptr, int* __restrict__ cursor) {
    __shared__ int s[SCAN_B];
    int t = threadIdx.x;
    int i = blockIdx.x * SCAN_B + t;
    int d = (i < N) ? deg[i] : 0;
    s[t] = d;
    __syncthreads();
    for (int o = 1; o < SCAN_B; o <<= 1) {
        int v = (t >= o) ? s[t - o] : 0;
        __syncthreads();
        s[t] += v;
        __syncthreads();
    }
    int excl = s[t] - d + partial[blockIdx.x];
    if (i < N) {
        row_ptr[i] = excl;
        cursor[i] = excl;
        if (i == N - 1) row_ptr[N] = excl + d;
    }
}

// XCD-sliced scatter: 8 slice-replicas per edge chunk; slice = blockIdx&7 maps round-robin
// onto the 8 XCDs, so each XCD's L2 only sees writes to a 3.2 MB (<4 MB L2) slice of csr_se
// -> random int2 writes MERGE in L2 instead of 8x line-writeback amplification (was 198 MB).
// dst/src re-reads (8x) are absorbed by the shared 256 MB L3. Correctness does not depend
// on the block->XCD mapping; worst case equals the unsliced behavior.
__global__ __launch_bounds__(256) void k_scatter_sliced(const int* __restrict__ src, const int* __restrict__ dst,
                                                        int E, int sliceW,
                                                        int* __restrict__ cursor, int2* __restrict__ csr_se) {
    int slice = blockIdx.x & 7;
    int e = (blockIdx.x >> 3) * 256 + threadIdx.x;
    if (e >= E) return;
    int d = dst[e];
    int lo = slice * sliceW;
    if (d < lo || d >= lo + sliceW) return;   // each edge kept by exactly one slice
    int pos = atomicAdd(&cursor[d], 1);
    csr_se[pos] = make_int2(src[e], e);
}

// ---------------- prep: xt1 = x @ Wm1[0:64,:], s1 = x @ Ws1 + bs1 ----------------
__global__ __launch_bounds__(256) void k_prep(const float* __restrict__ x,
                                              const float* __restrict__ Wm1,
                                              const float* __restrict__ Ws1,
                                              const float* __restrict__ bs1,
                                              int N, float* __restrict__ xt1, float* __restrict__ s1) {
    int t = blockIdx.x * blockDim.x + threadIdx.x;
    int n = t >> 4, f = t & 15;
    if (n >= N) return;
    const float4* xr4 = (const float4*)(x + (size_t)n * D_INF);
    float am = 0.f, as = bs1[f];
#pragma unroll
    for (int k4 = 0; k4 < 16; k4++) {
        float4 v = xr4[k4];
        int k = 4 * k4;
        am += v.x * Wm1[(k + 0) * HF + f]; as += v.x * Ws1[(k + 0) * HF + f];
        am += v.y * Wm1[(k + 1) * HF + f]; as += v.y * Ws1[(k + 1) * HF + f];
        am += v.z * Wm1[(k + 2) * HF + f]; as += v.z * Ws1[(k + 2) * HF + f];
        am += v.w * Wm1[(k + 3) * HF + f]; as += v.w * Ws1[(k + 3) * HF + f];
    }
    size_t idx = (size_t)n * HF + f;
    xt1[idx] = am;
    s1[idx]  = as;
}

// ---------------- conv1 fused: gather + node MLP -> xt2, h2base ----------------
// wave per node: 4 edge-slots x 16 features; no LDS, no atomics.
// Gather loop unrolled x4: 4 independent int2 index loads then 8 gathers per thread
// -> 16 gather lines in flight per wave (latency hedge).
// After the two xor-reduces ALL 64 lanes hold the full sums for feature f=lane&15,
// so the 16-wide node MLP runs in-wave (4 redundant copies, free) -- no aggm/agge round trip.
// h1 = relu(aggm + deg*b1 + agge@Wm1[64:80] + s1);  xt2 = h1@Wm2[0:16];
// h2base = h1@Ws2 + bs2 + agge@Wm2[16:32]
__global__ __launch_bounds__(256) void k_conv1f(const float* __restrict__ xt1, const float* __restrict__ eattr,
                                                const int2* __restrict__ csr_se, const int* __restrict__ row_ptr,
                                                const float* __restrict__ s1,
                                                const float* __restrict__ Wm1, const float* __restrict__ b1,
                                                const float* __restrict__ Wm2,
                                                const float* __restrict__ Ws2, const float* __restrict__ bs2,
                                                int N, float* __restrict__ xt2, float* __restrict__ h2base) {
    int lane = threadIdx.x & 63;
    int node = (int)((blockIdx.x * blockDim.x + threadIdx.x) >> 6);
    if (node >= N) return;
    int sub = lane >> 4, f = lane & 15;
    int r0 = row_ptr[node], r1 = row_ptr[node + 1];
    float degf = (float)(r1 - r0);
    float am = 0.f, ae = 0.f;
    int j = r0 + sub;
    for (; j + 12 < r1; j += 16) {         // unroll x4: indices j, j+4, j+8, j+12
        int2 se0 = csr_se[j];
        int2 se1 = csr_se[j + 4];
        int2 se2 = csr_se[j + 8];
        int2 se3 = csr_se[j + 12];
        float m0 = xt1[(size_t)se0.x * HF + f];
        float m1 = xt1[(size_t)se1.x * HF + f];
        float m2 = xt1[(size_t)se2.x * HF + f];
        float m3 = xt1[(size_t)se3.x * HF + f];
        float e0 = __builtin_nontemporal_load(eattr + (size_t)se0.y * DEF + f);
        float e1 = __builtin_nontemporal_load(eattr + (size_t)se1.y * DEF + f);
        float e2 = __builtin_nontemporal_load(eattr + (size_t)se2.y * DEF + f);
        float e3 = __builtin_nontemporal_load(eattr + (size_t)se3.y * DEF + f);
        am += (m0 + m1) + (m2 + m3);
        ae += (e0 + e1) + (e2 + e3);
    }
    for (; j < r1; j += 4) {               // remainder (0..3 indices for this sub)
        int2 se = csr_se[j];
        am += xt1[(size_t)se.x * HF + f];
        ae += __builtin_nontemporal_load(eattr + (size_t)se.y * DEF + f);
    }
    am += __shfl_xor(am, 16); am += __shfl_xor(am, 32);
    ae += __shfl_xor(ae, 16); ae += __shfl_xor(ae, 32);

    size_t idx = (size_t)node * HF + f;
    float acc = am + degf * b1[f] + s1[idx];
#pragma unroll
    for (int k = 0; k < HF; k++) {
        acc += __shfl(ae, k, 16) * Wm1[(D_INF + k) * HF + f];
    }
    float h1 = fmaxf(acc, 0.f);
    float xv = 0.f, hb = bs2[f];
#pragma unroll
    for (int k = 0; k < HF; k++) {
        float hk = __shfl(h1, k, 16);
        float ak = __shfl(ae, k, 16);
        xv += hk * Wm2[k * HF + f];
        hb += hk * Ws2[k * HF + f];
        hb += ak * Wm2[(HF + k) * HF + f];
    }
    if (lane < 16) {
        xt2[idx]    = xv;
        h2base[idx] = hb;
    }
}

// ---------------- conv2 fused: gather + final projection -> out ----------------
// h2 = sum xt2[src] + deg*b2 + h2base;  out = h2 @ W3 + b3  (width-16 shfl broadcast)
__global__ __launch_bounds__(256) void k_conv2f(const float* __restrict__ xt2,
                                                const int2* __restrict__ csr_se, const int* __restrict__ row_ptr,
                                                const float* __restrict__ h2base, const float* __restrict__ b2,
                                                const float* __restrict__ W3, const float* __restrict__ b3,
                                                int N, float* __restrict__ out) {
    int lane = threadIdx.x & 63;
    int node = (int)((blockIdx.x * blockDim.x + threadIdx.x) >> 6);
    if (node >= N) return;
    int sub = lane >> 4, f = lane & 15;
    int r0 = row_ptr[node], r1 = row_ptr[node + 1];
    float acc = 0.f;
    int j = r0 + sub;
    for (; j + 12 < r1; j += 16) {         // unroll x4
        int s0 = csr_se[j].x;
        int s1i = csr_se[j + 4].x;
        int s2 = csr_se[j + 8].x;
        int s3 = csr_se[j + 12].x;
        acc += xt2[(size_t)s0 * HF + f] + xt2[(size_t)s1i * HF + f];
        acc += xt2[(size_t)s2 * HF + f] + xt2[(size_t)s3 * HF + f];
    }
    for (; j < r1; j += 4) acc += xt2[(size_t)csr_se[j].x * HF + f];
    acc += __shfl_xor(acc, 16);
    acc += __shfl_xor(acc, 32);

    float h2 = acc + (float)(r1 - r0) * b2[f] + h2base[(size_t)node * HF + f];
    float o = b3[lane];
#pragma unroll
    for (int k = 0; k < HF; k++) {
        o += __shfl(h2, k, 16) * W3[k * D_INF + lane];   // segments identical -> width-16 ok
    }
    out[(size_t)node * D_INF + lane] = o;
}

// ---------------- launch ----------------

static inline size_t align256(size_t x) { return (x + 255) & ~(size_t)255; }

extern "C" void kernel_launch(void* const* d_in, const int* in_sizes, int n_in,
                              void* d_out, int out_size, void* d_ws, size_t ws_size,
                              hipStream_t stream) {
    const float* x    = (const float*)d_in[0];
    const int*   ei   = (const int*)d_in[1];
    const float* eatt = (const float*)d_in[2];
    const float* Wm1  = (const float*)d_in[3];
    const float* b1   = (const float*)d_in[4];
    const float* Ws1  = (const float*)d_in[5];
    const float* bs1  = (const float*)d_in[6];
    const float* Wm2  = (const float*)d_in[7];
    const float* b2   = (const float*)d_in[8];
    const float* Ws2  = (const float*)d_in[9];
    const float* bs2  = (const float*)d_in[10];
    const float* W3   = (const float*)d_in[11];
    const float* b3   = (const float*)d_in[12];
    float* out = (float*)d_out;

    int N = in_sizes[0] / D_INF;
    int E = in_sizes[1] / 2;
    const int* src = ei;
    const int* dst = ei + E;

    char* ws = (char*)d_ws;
    size_t off = 0;
    auto alloc = [&](size_t bytes) -> void* { void* p = ws + off; off = align256(off + bytes); return p; };

    int*   deg     = (int*)alloc((size_t)N * 4);
    int*   row_ptr = (int*)alloc((size_t)(N + 1) * 4);
    int*   cursor  = (int*)alloc((size_t)N * 4);
    int*   partial = (int*)alloc(1024 * 4);
    int2*  csr_se  = (int2*)alloc((size_t)E * 8);
    size_t szA = (size_t)N * HF * sizeof(float);
    float* xt1     = (float*)alloc(szA);
    float* s1      = (float*)alloc(szA);
    float* xt2     = (float*)alloc(szA);
    float* h2base  = (float*)alloc(szA);
    (void)ws_size; (void)n_in; (void)out_size;

    int P = (N + SCAN_B - 1) / SCAN_B;   // 391 for N=100k; k_scan_top handles P<=1024

    hipMemsetAsync(deg, 0, (size_t)N * 4, stream);

    dim3 blk(256);
    int gN16 = (N * HF + 255) / 256;
    int sliceW = (N + 7) / 8;            // node-slice width per XCD replica
    int eChunks = (E + 255) / 256;

    k_hist        <<<dim3(eChunks), blk, 0, stream>>>(dst, E, deg);
    k_scan_partial<<<dim3(P), dim3(SCAN_B), 0, stream>>>(deg, N, partial);
    k_scan_top    <<<dim3(1), dim3(1024), 0, stream>>>(partial, P);
    k_scan_final  <<<dim3(P), dim3(SCAN_B), 0, stream>>>(deg, partial, N, row_ptr, cursor);
    k_scatter_sliced<<<dim3(8 * eChunks), blk, 0, stream>>>(src, dst, E, sliceW, cursor, csr_se);

    k_prep  <<<dim3(gN16), blk, 0, stream>>>(x, Wm1, Ws1, bs1, N, xt1, s1);
    k_conv1f<<<dim3((N + 3) / 4), blk, 0, stream>>>(xt1, eatt, csr_se, row_ptr, s1,
                                                    Wm1, b1, Wm2, Ws2, bs2, N, xt2, h2base);
    k_conv2f<<<dim3((N + 3) / 4), blk, 0, stream>>>(xt2, csr_se, row_ptr, h2base, b2,
                                                    W3, b3, N, out);
}